// Round 1
// baseline (1983.261 us; speedup 1.0000x reference)
//
#include <hip/hip_runtime.h>
#include <hip/hip_bf16.h>
#include <math.h>

// Problem constants (fixed by reference): S=4, B=1, C=128, h=w=d=10
// N = 1000, L = S*N = 4000, nL = 2, H = 8, Dh = 16, scale = 0.25
#define LL 4000
#define CC 128
#define NN 1000
#define NLAYER 2

// ---------------------------------------------------------------------------
// tokenize: z[S,1,C,N] + seq_embed[S,C] -> tok[L,C]   (tok[(s*N+n)*C+c])
__global__ void tokenize_kernel(const float* __restrict__ z,
                                const float* __restrict__ se,
                                float* __restrict__ tok) {
    int idx = blockIdx.x * blockDim.x + threadIdx.x;   // over L*C = 512000
    if (idx >= LL * CC) return;
    int c = idx & (CC - 1);
    int t = idx >> 7;              // s*N + n
    int s = t / NN;
    int n = t - s * NN;
    tok[idx] = z[(s * CC + c) * NN + n] + se[s * CC + c];
}

// detokenize: tok[L,C] -> out[(s*C+c)*N + n]
__global__ void detok_kernel(const float* __restrict__ tok,
                             float* __restrict__ out) {
    int idx = blockIdx.x * blockDim.x + threadIdx.x;   // over 512000 outputs
    if (idx >= LL * CC) return;
    int n = idx % NN;
    int sc = idx / NN;             // s*C + c
    int c = sc & (CC - 1);
    int s = sc >> 7;
    out[idx] = tok[(s * NN + n) * CC + c];
}

// per-key softmax bias: kb[l*L + j] = beta[l] * log(r[j/N])
// (row term beta*log(r_i) is softmax-invariant; clamp is inactive since
//  r in [0.1,1] => r_i*r_j >= 0.01 >> 1e-8)
__global__ void kbias_kernel(const float* __restrict__ r,
                             const float* __restrict__ beta,
                             float* __restrict__ kb) {
    int idx = blockIdx.x * blockDim.x + threadIdx.x;
    if (idx >= NLAYER * LL) return;
    int l = idx / LL;
    int j = idx - l * LL;
    kb[idx] = beta[l] * __logf(r[j / NN]);
}

// ---------------------------------------------------------------------------
// Generic GEMM: out[M,N] = act(A[M,K] @ W[K,N] + bias)
// grid: (M/2, N/128), block 256. W k-tile (128 x 128-col chunk) staged in LDS.
__global__ void gemm_kernel(const float* __restrict__ A,
                            const float* __restrict__ W,
                            const float* __restrict__ bias,
                            float* __restrict__ out,
                            int M, int K, int N, int act) {
    __shared__ float wlds[128 * 128];                  // 64 KB
    int tid = threadIdx.x;
    int colLocal = tid & 127;
    int rowLocal = tid >> 7;                           // 0..1
    int col0 = blockIdx.y * 128;
    int row  = blockIdx.x * 2 + rowLocal;
    int col  = col0 + colLocal;
    float acc = 0.f;
    for (int k0 = 0; k0 < K; k0 += 128) {
        for (int i = tid; i < 128 * 128; i += 256) {
            int kk = i >> 7, cc = i & 127;
            wlds[i] = W[(size_t)(k0 + kk) * N + col0 + cc];
        }
        __syncthreads();
        if (row < M) {
            const float* arow = A + (size_t)row * K + k0;
            #pragma unroll 8
            for (int kk = 0; kk < 128; ++kk)
                acc = fmaf(arow[kk], wlds[kk * 128 + colLocal], acc);
        }
        __syncthreads();
    }
    if (row < M) {
        if (bias) acc += bias[col];
        if (act == 1)  // exact GELU (matches jax approximate=False)
            acc = 0.5f * acc * (1.f + erff(acc * 0.70710678118654752f));
        out[(size_t)row * N + col] = acc;
    }
}

// ---------------------------------------------------------------------------
// Flash attention, fp32. One query per thread, per-head. K/V tiles in LDS.
#define ABQ 128   // queries per block (= blockDim.x)
#define ATK 128   // keys per LDS tile
__global__ void attn_kernel(const float* __restrict__ Q,
                            const float* __restrict__ K,
                            const float* __restrict__ V,
                            const float* __restrict__ kb,
                            float* __restrict__ out) {
    __shared__ float kl[ATK][16];
    __shared__ float vl[ATK][16];
    __shared__ float bl[ATK];
    int h  = blockIdx.y;
    int qi = blockIdx.x * ABQ + threadIdx.x;
    bool valid = qi < LL;
    size_t qoff = (size_t)qi * CC + h * 16;
    float q[16], o[16];
    if (valid) {
        #pragma unroll
        for (int d = 0; d < 16; ++d) q[d] = Q[qoff + d] * 0.25f;  // Dh^-0.5
    }
    #pragma unroll
    for (int d = 0; d < 16; ++d) o[d] = 0.f;
    float m = -1e30f, lsum = 0.f;

    for (int j0 = 0; j0 < LL; j0 += ATK) {
        int nk = min(ATK, LL - j0);
        for (int i = threadIdx.x; i < nk * 16; i += ABQ) {
            int jj = i >> 4, dd = i & 15;
            size_t goff = (size_t)(j0 + jj) * CC + h * 16 + dd;
            kl[jj][dd] = K[goff];
            vl[jj][dd] = V[goff];
        }
        for (int i = threadIdx.x; i < nk; i += ABQ) bl[i] = kb[j0 + i];
        __syncthreads();
        if (valid) {
            for (int jj = 0; jj < nk; ++jj) {
                float s = bl[jj];
                #pragma unroll
                for (int d = 0; d < 16; ++d) s = fmaf(q[d], kl[jj][d], s);
                float p;
                if (s > m) {                     // rare: rescale state
                    float corr = __expf(m - s);
                    lsum *= corr;
                    #pragma unroll
                    for (int d = 0; d < 16; ++d) o[d] *= corr;
                    m = s;
                    p = 1.f;
                } else {
                    p = __expf(s - m);
                }
                lsum += p;
                #pragma unroll
                for (int d = 0; d < 16; ++d) o[d] = fmaf(p, vl[jj][d], o[d]);
            }
        }
        __syncthreads();
    }
    if (valid) {
        float inv = 1.f / lsum;
        #pragma unroll
        for (int d = 0; d < 16; ++d) out[qoff + d] = o[d] * inv;
    }
}

// ---------------------------------------------------------------------------
// Fused residual-add + LayerNorm over C=128. One wave per row.
__global__ void ln_kernel(const float* __restrict__ X,
                          const float* __restrict__ R,
                          const float* __restrict__ g,
                          const float* __restrict__ b,
                          float* __restrict__ out) {
    int row  = blockIdx.x;
    int lane = threadIdx.x;                 // 0..63
    size_t off = (size_t)row * CC;
    float x0 = X[off + lane]      + R[off + lane];
    float x1 = X[off + 64 + lane] + R[off + 64 + lane];
    float s  = x0 + x1;
    float s2 = x0 * x0 + x1 * x1;
    #pragma unroll
    for (int w = 32; w >= 1; w >>= 1) {
        s  += __shfl_xor(s,  w);
        s2 += __shfl_xor(s2, w);
    }
    float mu   = s * (1.f / CC);
    float var  = s2 * (1.f / CC) - mu * mu;
    float rstd = rsqrtf(var + 1e-5f);
    out[off + lane]      = (x0 - mu) * rstd * g[lane]      + b[lane];
    out[off + 64 + lane] = (x1 - mu) * rstd * g[lane + 64] + b[lane + 64];
}

// ---------------------------------------------------------------------------
extern "C" void kernel_launch(void* const* d_in, const int* in_sizes, int n_in,
                              void* d_out, int out_size, void* d_ws, size_t ws_size,
                              hipStream_t stream) {
    const float* z    = (const float*)d_in[0];
    const float* r    = (const float*)d_in[1];
    const float* se   = (const float*)d_in[2];
    const float* Wq   = (const float*)d_in[3];
    const float* Wk   = (const float*)d_in[4];
    const float* Wv   = (const float*)d_in[5];
    const float* Wp   = (const float*)d_in[6];
    const float* beta = (const float*)d_in[7];
    const float* ln1g = (const float*)d_in[8];
    const float* ln1b = (const float*)d_in[9];
    const float* w1   = (const float*)d_in[10];
    const float* b1   = (const float*)d_in[11];
    const float* w2   = (const float*)d_in[12];
    const float* b2   = (const float*)d_in[13];
    const float* ln2g = (const float*)d_in[14];
    const float* ln2b = (const float*)d_in[15];
    float* out = (float*)d_out;

    float* ws    = (float*)d_ws;
    float* tok   = ws;                    // 512000
    float* Qb    = tok  + LL * CC;        // 512000
    float* Kb    = Qb   + LL * CC;
    float* Vb    = Kb   + LL * CC;
    float* att   = Vb   + LL * CC;
    float* prj   = att  + LL * CC;
    float* hdn   = prj  + LL * CC;        // 4000*512 = 2,048,000
    float* kbias = hdn  + LL * 4 * CC;    // 8000
    // total ~20.6 MB of workspace

    tokenize_kernel<<<2000, 256, 0, stream>>>(z, se, tok);
    kbias_kernel<<<(NLAYER * LL + 255) / 256, 256, 0, stream>>>(r, beta, kbias);

    for (int l = 0; l < NLAYER; ++l) {
        const float* wq = Wq + (size_t)l * CC * CC;
        const float* wk = Wk + (size_t)l * CC * CC;
        const float* wv = Wv + (size_t)l * CC * CC;
        const float* wp = Wp + (size_t)l * CC * CC;
        gemm_kernel<<<dim3(LL / 2, 1), 256, 0, stream>>>(tok, wq, nullptr, Qb, LL, CC, CC, 0);
        gemm_kernel<<<dim3(LL / 2, 1), 256, 0, stream>>>(tok, wk, nullptr, Kb, LL, CC, CC, 0);
        gemm_kernel<<<dim3(LL / 2, 1), 256, 0, stream>>>(tok, wv, nullptr, Vb, LL, CC, CC, 0);
        attn_kernel<<<dim3((LL + ABQ - 1) / ABQ, 8), ABQ, 0, stream>>>(Qb, Kb, Vb, kbias + l * LL, att);
        gemm_kernel<<<dim3(LL / 2, 1), 256, 0, stream>>>(att, wp, nullptr, prj, LL, CC, CC, 0);
        ln_kernel<<<LL, 64, 0, stream>>>(prj, tok, ln1g + l * CC, ln1b + l * CC, tok);
    }

    // FFN: hdn = GELU(tok @ w1 + b1); tok = LN(hdn @ w2 + b2 + tok)
    gemm_kernel<<<dim3(LL / 2, 4), 256, 0, stream>>>(tok, w1, b1, hdn, LL, CC, 4 * CC, 1);
    gemm_kernel<<<dim3(LL / 2, 1), 256, 0, stream>>>(hdn, w2, b2, prj, LL, 4 * CC, CC, 0);
    ln_kernel<<<LL, 64, 0, stream>>>(prj, tok, ln2g, ln2b, tok);

    detok_kernel<<<2000, 256, 0, stream>>>(tok, out);
}

// Round 2
// 629.207 us; speedup vs baseline: 3.1520x; 3.1520x over previous
//
#include <hip/hip_runtime.h>
#include <hip/hip_bf16.h>
#include <math.h>

// Problem constants: S=4, B=1, C=128, h=w=d=10 -> N=1000, L=4000, nL=2, H=8, Dh=16
#define LL 4000
#define CC 128
#define NN 1000
#define NLAYER 2

typedef __attribute__((ext_vector_type(4))) short bf16x4;
typedef __attribute__((ext_vector_type(4))) float f32x4;

__device__ __forceinline__ short bf16rd(float f) {
    unsigned u = __builtin_bit_cast(unsigned, f);
    return (short)((u + 0x8000u) >> 16);   // round-half-up to bf16
}

// ---------------------------------------------------------------------------
// tokenize: z[S,1,C,N] + seq_embed[S,C] -> tok[L,C]
__global__ void tokenize_kernel(const float* __restrict__ z,
                                const float* __restrict__ se,
                                float* __restrict__ tok) {
    int idx = blockIdx.x * blockDim.x + threadIdx.x;
    if (idx >= LL * CC) return;
    int c = idx & (CC - 1);
    int t = idx >> 7;
    int s = t / NN;
    int n = t - s * NN;
    tok[idx] = z[(s * CC + c) * NN + n] + se[s * CC + c];
}

// detokenize: tok[L,C] -> out[(s*C+c)*N + n]
__global__ void detok_kernel(const float* __restrict__ tok,
                             float* __restrict__ out) {
    int idx = blockIdx.x * blockDim.x + threadIdx.x;
    if (idx >= LL * CC) return;
    int n = idx % NN;
    int sc = idx / NN;
    int c = sc & (CC - 1);
    int s = sc >> 7;
    out[idx] = tok[(s * NN + n) * CC + c];
}

// kb[l*L + j] = beta[l] * log(r[j/N])   (row term is softmax-invariant)
__global__ void kbias_kernel(const float* __restrict__ r,
                             const float* __restrict__ beta,
                             float* __restrict__ kb) {
    int idx = blockIdx.x * blockDim.x + threadIdx.x;
    if (idx >= NLAYER * LL) return;
    int l = idx / LL;
    int j = idx - l * LL;
    kb[idx] = beta[l] * __logf(r[j / NN]);
}

// ---------------------------------------------------------------------------
// Generic GEMM: out[M,N] = act(A[M,K] @ W[K,N] + bias)
// act: 0 = none (fp32 out), 1 = exact GELU (fp32 out), 2 = bf16 out (no bias)
__global__ void gemm_kernel(const float* __restrict__ A,
                            const float* __restrict__ W,
                            const float* __restrict__ bias,
                            void* __restrict__ out,
                            int M, int K, int N, int act) {
    __shared__ float wlds[128 * 128];
    int tid = threadIdx.x;
    int colLocal = tid & 127;
    int rowLocal = tid >> 7;
    int col0 = blockIdx.y * 128;
    int row  = blockIdx.x * 2 + rowLocal;
    int col  = col0 + colLocal;
    float acc = 0.f;
    for (int k0 = 0; k0 < K; k0 += 128) {
        for (int i = tid; i < 128 * 128; i += 256) {
            int kk = i >> 7, cc = i & 127;
            wlds[i] = W[(size_t)(k0 + kk) * N + col0 + cc];
        }
        __syncthreads();
        if (row < M) {
            const float* arow = A + (size_t)row * K + k0;
            #pragma unroll 8
            for (int kk = 0; kk < 128; ++kk)
                acc = fmaf(arow[kk], wlds[kk * 128 + colLocal], acc);
        }
        __syncthreads();
    }
    if (row < M) {
        if (act == 2) {
            ((__hip_bfloat16*)out)[(size_t)row * N + col] = __float2bfloat16(acc);
        } else {
            if (bias) acc += bias[col];
            if (act == 1)
                acc = 0.5f * acc * (1.f + erff(acc * 0.70710678118654752f));
            ((float*)out)[(size_t)row * N + col] = acc;
        }
    }
}

// ---------------------------------------------------------------------------
// MFMA flash attention. One wave = 16 queries x 1 head. 32 keys/iter.
// S^T = mfma(K_frag, Q_frag): lane holds S[key=4g+r][q=lane&15] (C-layout),
// which is exactly the B-operand layout for O^T += mfma(V^T_frag, P_frag).
__global__ __launch_bounds__(64) void attn_mfma_kernel(
        const short* __restrict__ Qb, const short* __restrict__ Kb,
        const short* __restrict__ Vb, const float* __restrict__ kb,
        float* __restrict__ out) {
    const int lane = threadIdx.x;
    const int lq = lane & 15;
    const int g  = lane >> 4;
    const int h  = blockIdx.y;
    const int q0 = blockIdx.x * 16;
    const int hd0 = h * 16;

    // Q-frag (B operand): Q[q0+lq][hd0 + 4g + j], j=0..3
    const bf16x4 qf = *(const bf16x4*)(Qb + (size_t)(q0 + lq) * CC + hd0 + 4 * g);

    const short* kp = Kb + (size_t)lq * CC + hd0 + 4 * g;      // + key*CC
    const short* vp = Vb + (size_t)(4 * g) * CC + hd0 + lq;    // + key*CC

    f32x4 o = {0.f, 0.f, 0.f, 0.f};
    float m = -INFINITY, lsum = 0.f;

    bf16x4 kf0, kf1, vf0, vf1;
    f32x4 b0, b1;

    auto load_tile = [&](int k0, bf16x4& K0, bf16x4& K1, f32x4& B0, f32x4& B1,
                         bf16x4& V0, bf16x4& V1) {
        K0 = *(const bf16x4*)(kp + (size_t)k0 * CC);
        K1 = *(const bf16x4*)(kp + (size_t)(k0 + 16) * CC);
        B0 = *(const f32x4*)(kb + k0 + 4 * g);
        B1 = *(const f32x4*)(kb + k0 + 16 + 4 * g);
        const short* v0 = vp + (size_t)k0 * CC;
        const short* v1 = v0 + (size_t)16 * CC;
        V0 = (bf16x4){v0[0], v0[CC], v0[2 * CC], v0[3 * CC]};
        V1 = (bf16x4){v1[0], v1[CC], v1[2 * CC], v1[3 * CC]};
    };

    load_tile(0, kf0, kf1, b0, b1, vf0, vf1);

    for (int k0 = 0; k0 < LL; k0 += 32) {
        // prefetch next tile (wrap to 0 on last iter to stay branch-free)
        int kn = (k0 + 32 < LL) ? (k0 + 32) : 0;
        bf16x4 nk0, nk1, nv0, nv1;
        f32x4 nb0, nb1;
        load_tile(kn, nk0, nk1, nb0, nb1, nv0, nv1);

        const f32x4 z = {0.f, 0.f, 0.f, 0.f};
        f32x4 s0 = __builtin_amdgcn_mfma_f32_16x16x16bf16_1k(kf0, qf, z, 0, 0, 0);
        f32x4 s1 = __builtin_amdgcn_mfma_f32_16x16x16bf16_1k(kf1, qf, z, 0, 0, 0);
        #pragma unroll
        for (int r = 0; r < 4; ++r) {
            s0[r] = fmaf(s0[r], 0.25f, b0[r]);   // Dh^-0.5 scale + key bias
            s1[r] = fmaf(s1[r], 0.25f, b1[r]);
        }
        // tile max for this lane's query (across 8 regs, then across group)
        float pm = fmaxf(fmaxf(fmaxf(s0[0], s0[1]), fmaxf(s0[2], s0[3])),
                         fmaxf(fmaxf(s1[0], s1[1]), fmaxf(s1[2], s1[3])));
        pm = fmaxf(pm, __shfl_xor(pm, 16));
        pm = fmaxf(pm, __shfl_xor(pm, 32));
        float mn = fmaxf(m, pm);
        float corr = __expf(m - mn);

        float p0[4], p1[4];
        float ps = 0.f;
        #pragma unroll
        for (int r = 0; r < 4; ++r) {
            p0[r] = __expf(s0[r] - mn);
            p1[r] = __expf(s1[r] - mn);
            ps += p0[r] + p1[r];
        }
        ps += __shfl_xor(ps, 16);
        ps += __shfl_xor(ps, 32);
        lsum = fmaf(lsum, corr, ps);

        #pragma unroll
        for (int r = 0; r < 4; ++r) o[r] *= corr;

        bf16x4 pt0 = {bf16rd(p0[0]), bf16rd(p0[1]), bf16rd(p0[2]), bf16rd(p0[3])};
        bf16x4 pt1 = {bf16rd(p1[0]), bf16rd(p1[1]), bf16rd(p1[2]), bf16rd(p1[3])};

        o = __builtin_amdgcn_mfma_f32_16x16x16bf16_1k(vf0, pt0, o, 0, 0, 0);
        o = __builtin_amdgcn_mfma_f32_16x16x16bf16_1k(vf1, pt1, o, 0, 0, 0);
        m = mn;

        kf0 = nk0; kf1 = nk1; b0 = nb0; b1 = nb1; vf0 = nv0; vf1 = nv1;
    }

    float inv = 1.f / lsum;
    float* op = out + (size_t)(q0 + lq) * CC + hd0 + 4 * g;
    f32x4 res = {o[0] * inv, o[1] * inv, o[2] * inv, o[3] * inv};
    *(f32x4*)op = res;
}

// ---------------------------------------------------------------------------
// Fused residual-add + LayerNorm over C=128. One wave per row.
__global__ void ln_kernel(const float* __restrict__ X,
                          const float* __restrict__ R,
                          const float* __restrict__ g,
                          const float* __restrict__ b,
                          float* __restrict__ out) {
    int row  = blockIdx.x;
    int lane = threadIdx.x;
    size_t off = (size_t)row * CC;
    float x0 = X[off + lane]      + R[off + lane];
    float x1 = X[off + 64 + lane] + R[off + 64 + lane];
    float s  = x0 + x1;
    float s2 = x0 * x0 + x1 * x1;
    #pragma unroll
    for (int w = 32; w >= 1; w >>= 1) {
        s  += __shfl_xor(s,  w);
        s2 += __shfl_xor(s2, w);
    }
    float mu   = s * (1.f / CC);
    float var  = s2 * (1.f / CC) - mu * mu;
    float rstd = rsqrtf(var + 1e-5f);
    out[off + lane]      = (x0 - mu) * rstd * g[lane]      + b[lane];
    out[off + 64 + lane] = (x1 - mu) * rstd * g[lane + 64] + b[lane + 64];
}

// ---------------------------------------------------------------------------
extern "C" void kernel_launch(void* const* d_in, const int* in_sizes, int n_in,
                              void* d_out, int out_size, void* d_ws, size_t ws_size,
                              hipStream_t stream) {
    const float* z    = (const float*)d_in[0];
    const float* r    = (const float*)d_in[1];
    const float* se   = (const float*)d_in[2];
    const float* Wq   = (const float*)d_in[3];
    const float* Wk   = (const float*)d_in[4];
    const float* Wv   = (const float*)d_in[5];
    const float* Wp   = (const float*)d_in[6];
    const float* beta = (const float*)d_in[7];
    const float* ln1g = (const float*)d_in[8];
    const float* ln1b = (const float*)d_in[9];
    const float* w1   = (const float*)d_in[10];
    const float* b1   = (const float*)d_in[11];
    const float* w2   = (const float*)d_in[12];
    const float* b2   = (const float*)d_in[13];
    const float* ln2g = (const float*)d_in[14];
    const float* ln2b = (const float*)d_in[15];
    float* out = (float*)d_out;

    float* ws    = (float*)d_ws;
    float* tok   = ws;                     // 512000 f32
    float* att   = tok + LL * CC;          // 512000 f32
    float* prj   = att + LL * CC;          // 512000 f32
    float* hdn   = prj + LL * CC;          // 2,048,000 f32
    float* kbias = hdn + LL * 4 * CC;      // 8000 f32
    __hip_bfloat16* Qb16 = (__hip_bfloat16*)(kbias + NLAYER * LL);
    __hip_bfloat16* Kb16 = Qb16 + LL * CC;
    __hip_bfloat16* Vb16 = Kb16 + LL * CC; // +3 MB bf16; total ~17.4 MB

    tokenize_kernel<<<2000, 256, 0, stream>>>(z, se, tok);
    kbias_kernel<<<(NLAYER * LL + 255) / 256, 256, 0, stream>>>(r, beta, kbias);

    for (int l = 0; l < NLAYER; ++l) {
        const float* wq = Wq + (size_t)l * CC * CC;
        const float* wk = Wk + (size_t)l * CC * CC;
        const float* wv = Wv + (size_t)l * CC * CC;
        const float* wp = Wp + (size_t)l * CC * CC;
        gemm_kernel<<<dim3(LL / 2, 1), 256, 0, stream>>>(tok, wq, nullptr, Qb16, LL, CC, CC, 2);
        gemm_kernel<<<dim3(LL / 2, 1), 256, 0, stream>>>(tok, wk, nullptr, Kb16, LL, CC, CC, 2);
        gemm_kernel<<<dim3(LL / 2, 1), 256, 0, stream>>>(tok, wv, nullptr, Vb16, LL, CC, CC, 2);
        attn_mfma_kernel<<<dim3(LL / 16, 8), 64, 0, stream>>>(
            (const short*)Qb16, (const short*)Kb16, (const short*)Vb16,
            kbias + l * LL, att);
        gemm_kernel<<<dim3(LL / 2, 1), 256, 0, stream>>>(att, wp, nullptr, prj, LL, CC, CC, 0);
        ln_kernel<<<LL, 64, 0, stream>>>(prj, tok, ln1g + l * CC, ln1b + l * CC, tok);
    }

    gemm_kernel<<<dim3(LL / 2, 4), 256, 0, stream>>>(tok, w1, b1, hdn, LL, CC, 4 * CC, 1);
    gemm_kernel<<<dim3(LL / 2, 1), 256, 0, stream>>>(hdn, w2, b2, prj, LL, 4 * CC, CC, 0);
    ln_kernel<<<LL, 64, 0, stream>>>(prj, tok, ln2g, ln2b, tok);

    detok_kernel<<<2000, 256, 0, stream>>>(tok, out);
}

// Round 3
// 239.749 us; speedup vs baseline: 8.2722x; 2.6244x over previous
//
#include <hip/hip_runtime.h>
#include <hip/hip_bf16.h>
#include <math.h>

// Problem constants: S=4, B=1, C=128, h=w=d=10 -> N=1000, L=4000, nL=2, H=8, Dh=16
#define LL 4000
#define CC 128
#define NN 1000
#define NLAYER 2

typedef __attribute__((ext_vector_type(4))) short bf16x4;
typedef __attribute__((ext_vector_type(8))) short short8;
typedef __attribute__((ext_vector_type(4))) float f32x4;

__device__ __forceinline__ short bf16rd(float f) {
    unsigned u = __builtin_bit_cast(unsigned, f);
    return (short)((u + 0x8000u) >> 16);
}
__device__ __forceinline__ short bf16rne(float f) {
    return __builtin_bit_cast(short, __float2bfloat16(f));
}

// ---------------------------------------------------------------------------
// tokenize: z[S,1,C,N] + seq_embed[S,C] -> tok[L,C] (f32) + tokb (bf16)
__global__ void tokenize_kernel(const float* __restrict__ z,
                                const float* __restrict__ se,
                                float* __restrict__ tok,
                                short* __restrict__ tokb) {
    int idx = blockIdx.x * blockDim.x + threadIdx.x;
    if (idx >= LL * CC) return;
    int c = idx & (CC - 1);
    int t = idx >> 7;
    int s = t / NN;
    int n = t - s * NN;
    float v = z[(s * CC + c) * NN + n] + se[s * CC + c];
    tok[idx] = v;
    tokb[idx] = bf16rne(v);
}

// detokenize: tok[L,C] -> out[(s*C+c)*N + n]
__global__ void detok_kernel(const float* __restrict__ tok,
                             float* __restrict__ out) {
    int idx = blockIdx.x * blockDim.x + threadIdx.x;
    if (idx >= LL * CC) return;
    int n = idx % NN;
    int sc = idx / NN;
    int c = sc & (CC - 1);
    int s = sc >> 7;
    out[idx] = tok[(s * NN + n) * CC + c];
}

// kb[l*L + j] = beta[l] * log(r[j/N])   (row term is softmax-invariant)
__global__ void kbias_kernel(const float* __restrict__ r,
                             const float* __restrict__ beta,
                             float* __restrict__ kb) {
    int idx = blockIdx.x * blockDim.x + threadIdx.x;
    if (idx >= NLAYER * LL) return;
    int l = idx / LL;
    int j = idx - l * LL;
    kb[idx] = beta[l] * __logf(r[j / NN]);
}

// ---------------------------------------------------------------------------
// weight prep: bf16 + transpose -> Wt[N][K]
// layout: 8 mats 128x128 (Wq0,Wq1,Wk0,Wk1,Wv0,Wv1,Wp0,Wp1) then w1t[512,128], w2t[128,512]
__global__ void prep_weights(const float* __restrict__ Wq, const float* __restrict__ Wk,
                             const float* __restrict__ Wv, const float* __restrict__ Wp,
                             const float* __restrict__ w1, const float* __restrict__ w2,
                             short* __restrict__ wt8, short* __restrict__ w1t,
                             short* __restrict__ w2t) {
    int idx = blockIdx.x * blockDim.x + threadIdx.x;
    if (idx < 8 * 16384) {
        int m = idx >> 14, i = idx & 16383;
        int n = i >> 7, k = i & 127;
        const float* src = (m < 2) ? Wq + (size_t)m * 16384
                         : (m < 4) ? Wk + (size_t)(m - 2) * 16384
                         : (m < 6) ? Wv + (size_t)(m - 4) * 16384
                                   : Wp + (size_t)(m - 6) * 16384;
        wt8[idx] = bf16rne(src[k * 128 + n]);
    } else if (idx < 8 * 16384 + 65536) {
        int i = idx - 8 * 16384;
        int n = i >> 7, k = i & 127;
        w1t[i] = bf16rne(w1[(size_t)k * 512 + n]);
    } else if (idx < 8 * 16384 + 2 * 65536) {
        int i = idx - 8 * 16384 - 65536;
        int n = i >> 9, k = i & 511;
        w2t[i] = bf16rne(w2[(size_t)k * 128 + n]);
    }
}

// ---------------------------------------------------------------------------
// MFMA GEMM body: out[M,N] = act(A[M,K] @ Wt[N,K]^T + bias)
// block 256 = 4 waves; tile 16 rows x 128 cols; wave w -> col-tiles 2w, 2w+1
// flags: 1 = bf16 out, 2 = exact GELU
__device__ __forceinline__ void gemm_body(
        const short* __restrict__ A, const short* __restrict__ Wt,
        const float* __restrict__ bias, void* __restrict__ outp,
        int M, int K, int N, int flags, int row0, int col0) {
    __shared__ short Al[16][136];
    __shared__ short Wl[128][136];
    const int tid = threadIdx.x;
    const int lane = tid & 63;
    const int w = tid >> 6;
    const int lq = lane & 15, g = lane >> 4;

    f32x4 acc[2] = {{0.f,0.f,0.f,0.f},{0.f,0.f,0.f,0.f}};

    for (int kc = 0; kc < K; kc += 128) {
        {   // stage A tile: 16 x 128 shorts, one 16B chunk/thread
            int r = tid >> 4, c = (tid & 15) * 8;
            *(short8*)&Al[r][c] = *(const short8*)(A + (size_t)(row0 + r) * K + kc + c);
        }
        {   // stage W tile: 128 x 128 shorts, 8 chunks/thread
            int c = (tid & 15) * 8;
            int nb = tid >> 4;
            #pragma unroll
            for (int i = 0; i < 8; ++i) {
                int n = nb + i * 16;
                *(short8*)&Wl[n][c] = *(const short8*)(Wt + (size_t)(col0 + n) * K + kc + c);
            }
        }
        __syncthreads();
        bf16x4 af[8];
        #pragma unroll
        for (int ks = 0; ks < 8; ++ks)
            af[ks] = *(const bf16x4*)&Al[lq][ks * 16 + g * 4];
        #pragma unroll
        for (int ct = 0; ct < 2; ++ct) {
            int n = (w * 2 + ct) * 16 + lq;
            #pragma unroll
            for (int ks = 0; ks < 8; ++ks) {
                bf16x4 bfr = *(const bf16x4*)&Wl[n][ks * 16 + g * 4];
                acc[ct] = __builtin_amdgcn_mfma_f32_16x16x16bf16_1k(af[ks], bfr, acc[ct], 0, 0, 0);
            }
        }
        __syncthreads();
    }
    #pragma unroll
    for (int ct = 0; ct < 2; ++ct) {
        int col = col0 + (w * 2 + ct) * 16 + lq;
        float bv = bias ? bias[col] : 0.f;
        #pragma unroll
        for (int r = 0; r < 4; ++r) {
            int row = row0 + g * 4 + r;
            float v = acc[ct][r] + bv;
            if (flags & 2) v = 0.5f * v * (1.f + erff(v * 0.70710678118654752f));
            if (flags & 1)
                ((short*)outp)[(size_t)row * N + col] = bf16rne(v);
            else
                ((float*)outp)[(size_t)row * N + col] = v;
        }
    }
}

__global__ __launch_bounds__(256) void mfma_gemm(
        const short* __restrict__ A, const short* __restrict__ Wt,
        const float* __restrict__ bias, void* __restrict__ outp,
        int M, int K, int N, int flags) {
    gemm_body(A, Wt, bias, outp, M, K, N, flags,
              blockIdx.x * 16, blockIdx.y * 128);
}

// fused QKV: blockIdx.z selects weight/output; bf16 out
__global__ __launch_bounds__(256) void mfma_gemm3(
        const short* __restrict__ A,
        const short* __restrict__ W0, const short* __restrict__ W1,
        const short* __restrict__ W2,
        short* __restrict__ o0, short* __restrict__ o1, short* __restrict__ o2,
        int M, int K, int N) {
    const short* Wt = (blockIdx.z == 0) ? W0 : (blockIdx.z == 1) ? W1 : W2;
    short* o = (blockIdx.z == 0) ? o0 : (blockIdx.z == 1) ? o1 : o2;
    gemm_body(A, Wt, nullptr, o, M, K, N, 1, blockIdx.x * 16, 0);
}

// ---------------------------------------------------------------------------
// MFMA flash attention. One wave = 16 queries x 1 head. 32 keys/iter. bf16 out.
__global__ __launch_bounds__(64) void attn_mfma_kernel(
        const short* __restrict__ Qb, const short* __restrict__ Kb,
        const short* __restrict__ Vb, const float* __restrict__ kb,
        short* __restrict__ out) {
    const int lane = threadIdx.x;
    const int lq = lane & 15;
    const int g  = lane >> 4;
    const int h  = blockIdx.y;
    const int q0 = blockIdx.x * 16;
    const int hd0 = h * 16;

    const bf16x4 qf = *(const bf16x4*)(Qb + (size_t)(q0 + lq) * CC + hd0 + 4 * g);
    const short* kp = Kb + (size_t)lq * CC + hd0 + 4 * g;
    const short* vp = Vb + (size_t)(4 * g) * CC + hd0 + lq;

    f32x4 o = {0.f, 0.f, 0.f, 0.f};
    float m = -INFINITY, lsum = 0.f;

    bf16x4 kf0, kf1, vf0, vf1;
    f32x4 b0, b1;

    auto load_tile = [&](int k0, bf16x4& K0, bf16x4& K1, f32x4& B0, f32x4& B1,
                         bf16x4& V0, bf16x4& V1) {
        K0 = *(const bf16x4*)(kp + (size_t)k0 * CC);
        K1 = *(const bf16x4*)(kp + (size_t)(k0 + 16) * CC);
        B0 = *(const f32x4*)(kb + k0 + 4 * g);
        B1 = *(const f32x4*)(kb + k0 + 16 + 4 * g);
        const short* v0 = vp + (size_t)k0 * CC;
        const short* v1 = v0 + (size_t)16 * CC;
        V0 = (bf16x4){v0[0], v0[CC], v0[2 * CC], v0[3 * CC]};
        V1 = (bf16x4){v1[0], v1[CC], v1[2 * CC], v1[3 * CC]};
    };

    load_tile(0, kf0, kf1, b0, b1, vf0, vf1);

    for (int k0 = 0; k0 < LL; k0 += 32) {
        int kn = (k0 + 32 < LL) ? (k0 + 32) : 0;
        bf16x4 nk0, nk1, nv0, nv1;
        f32x4 nb0, nb1;
        load_tile(kn, nk0, nk1, nb0, nb1, nv0, nv1);

        const f32x4 z = {0.f, 0.f, 0.f, 0.f};
        f32x4 s0 = __builtin_amdgcn_mfma_f32_16x16x16bf16_1k(kf0, qf, z, 0, 0, 0);
        f32x4 s1 = __builtin_amdgcn_mfma_f32_16x16x16bf16_1k(kf1, qf, z, 0, 0, 0);
        #pragma unroll
        for (int r = 0; r < 4; ++r) {
            s0[r] = fmaf(s0[r], 0.25f, b0[r]);
            s1[r] = fmaf(s1[r], 0.25f, b1[r]);
        }
        float pm = fmaxf(fmaxf(fmaxf(s0[0], s0[1]), fmaxf(s0[2], s0[3])),
                         fmaxf(fmaxf(s1[0], s1[1]), fmaxf(s1[2], s1[3])));
        pm = fmaxf(pm, __shfl_xor(pm, 16));
        pm = fmaxf(pm, __shfl_xor(pm, 32));
        float mn = fmaxf(m, pm);
        float corr = __expf(m - mn);

        float p0[4], p1[4];
        float ps = 0.f;
        #pragma unroll
        for (int r = 0; r < 4; ++r) {
            p0[r] = __expf(s0[r] - mn);
            p1[r] = __expf(s1[r] - mn);
            ps += p0[r] + p1[r];
        }
        ps += __shfl_xor(ps, 16);
        ps += __shfl_xor(ps, 32);
        lsum = fmaf(lsum, corr, ps);

        #pragma unroll
        for (int r = 0; r < 4; ++r) o[r] *= corr;

        bf16x4 pt0 = {bf16rd(p0[0]), bf16rd(p0[1]), bf16rd(p0[2]), bf16rd(p0[3])};
        bf16x4 pt1 = {bf16rd(p1[0]), bf16rd(p1[1]), bf16rd(p1[2]), bf16rd(p1[3])};

        o = __builtin_amdgcn_mfma_f32_16x16x16bf16_1k(vf0, pt0, o, 0, 0, 0);
        o = __builtin_amdgcn_mfma_f32_16x16x16bf16_1k(vf1, pt1, o, 0, 0, 0);
        m = mn;

        kf0 = nk0; kf1 = nk1; b0 = nb0; b1 = nb1; vf0 = nv0; vf1 = nv1;
    }

    float inv = 1.f / lsum;
    bf16x4 res = {bf16rne(o[0] * inv), bf16rne(o[1] * inv),
                  bf16rne(o[2] * inv), bf16rne(o[3] * inv)};
    *(bf16x4*)(out + (size_t)(q0 + lq) * CC + hd0 + 4 * g) = res;
}

// ---------------------------------------------------------------------------
// Fused residual-add + LayerNorm over C=128; writes f32 + bf16 copies.
__global__ void ln_kernel(const float* __restrict__ X,
                          const float* __restrict__ R,
                          const float* __restrict__ g,
                          const float* __restrict__ b,
                          float* __restrict__ out,
                          short* __restrict__ outb) {
    int row  = blockIdx.x;
    int lane = threadIdx.x;
    size_t off = (size_t)row * CC;
    float x0 = X[off + lane]      + R[off + lane];
    float x1 = X[off + 64 + lane] + R[off + 64 + lane];
    float s  = x0 + x1;
    float s2 = x0 * x0 + x1 * x1;
    #pragma unroll
    for (int w = 32; w >= 1; w >>= 1) {
        s  += __shfl_xor(s,  w);
        s2 += __shfl_xor(s2, w);
    }
    float mu   = s * (1.f / CC);
    float var  = s2 * (1.f / CC) - mu * mu;
    float rstd = rsqrtf(var + 1e-5f);
    float y0 = (x0 - mu) * rstd * g[lane]      + b[lane];
    float y1 = (x1 - mu) * rstd * g[lane + 64] + b[lane + 64];
    out[off + lane]      = y0;
    out[off + 64 + lane] = y1;
    outb[off + lane]      = bf16rne(y0);
    outb[off + 64 + lane] = bf16rne(y1);
}

// ---------------------------------------------------------------------------
extern "C" void kernel_launch(void* const* d_in, const int* in_sizes, int n_in,
                              void* d_out, int out_size, void* d_ws, size_t ws_size,
                              hipStream_t stream) {
    const float* z    = (const float*)d_in[0];
    const float* r    = (const float*)d_in[1];
    const float* se   = (const float*)d_in[2];
    const float* Wq   = (const float*)d_in[3];
    const float* Wk   = (const float*)d_in[4];
    const float* Wv   = (const float*)d_in[5];
    const float* Wp   = (const float*)d_in[6];
    const float* beta = (const float*)d_in[7];
    const float* ln1g = (const float*)d_in[8];
    const float* ln1b = (const float*)d_in[9];
    const float* w1   = (const float*)d_in[10];
    const float* b1   = (const float*)d_in[11];
    const float* w2   = (const float*)d_in[12];
    const float* b2   = (const float*)d_in[13];
    const float* ln2g = (const float*)d_in[14];
    const float* ln2b = (const float*)d_in[15];
    float* out = (float*)d_out;

    float* ws    = (float*)d_ws;
    float* tok   = ws;                       // 512000 f
    float* prj   = tok + LL * CC;            // 512000 f
    float* kbias = prj + LL * CC;            // 8000 f
    short* hdn   = (short*)(kbias + NLAYER * LL);  // 2,048,000 sh
    short* tokb  = hdn  + LL * 4 * CC;       // 512000 sh
    short* attb  = tokb + LL * CC;
    short* Qb    = attb + LL * CC;
    short* Kb    = Qb   + LL * CC;
    short* Vb    = Kb   + LL * CC;
    short* wt8   = Vb   + LL * CC;           // 8*16384
    short* w1t   = wt8  + 8 * 16384;         // 65536
    short* w2t   = w1t  + 65536;             // 65536  (total ~14 MB)

    prep_weights<<<1024, 256, 0, stream>>>(Wq, Wk, Wv, Wp, w1, w2, wt8, w1t, w2t);
    tokenize_kernel<<<2000, 256, 0, stream>>>(z, se, tok, tokb);
    kbias_kernel<<<32, 256, 0, stream>>>(r, beta, kbias);

    for (int l = 0; l < NLAYER; ++l) {
        const short* wqt = wt8 + (size_t)(0 * 2 + l) * 16384;
        const short* wkt = wt8 + (size_t)(1 * 2 + l) * 16384;
        const short* wvt = wt8 + (size_t)(2 * 2 + l) * 16384;
        const short* wpt = wt8 + (size_t)(3 * 2 + l) * 16384;
        mfma_gemm3<<<dim3(LL / 16, 1, 3), 256, 0, stream>>>(
            tokb, wqt, wkt, wvt, Qb, Kb, Vb, LL, CC, CC);
        attn_mfma_kernel<<<dim3(LL / 16, 8), 64, 0, stream>>>(
            Qb, Kb, Vb, kbias + l * LL, attb);
        mfma_gemm<<<dim3(LL / 16, 1), 256, 0, stream>>>(
            attb, wpt, nullptr, prj, LL, CC, CC, 0);
        ln_kernel<<<LL, 64, 0, stream>>>(prj, tok, ln1g + l * CC, ln1b + l * CC,
                                         tok, tokb);
    }

    mfma_gemm<<<dim3(LL / 16, 4), 256, 0, stream>>>(tokb, w1t, b1, hdn, LL, CC, 4 * CC, 1 | 2);
    mfma_gemm<<<dim3(LL / 16, 1), 256, 0, stream>>>(hdn, w2t, b2, prj, LL, 4 * CC, CC, 0);
    ln_kernel<<<LL, 64, 0, stream>>>(prj, tok, ln2g, ln2b, tok, tokb);

    detok_kernel<<<2000, 256, 0, stream>>>(tok, out);
}